// Round 5
// baseline (646.074 us; speedup 1.0000x reference)
//
#include <hip/hip_runtime.h>

#define B_ 16
#define C_ 512
#define K_ 128
#define N_ 4096   // H*W = 64*64
#define NKEEP 51  // int(0.1 * 512)
#define NSPLIT 16 // n-reduction split for qk (4 image rows per block)

// ---------------------------------------------------------------------------
// K1: depthwise 3x3 conv (SAME, stride 1) for k and v from x_kv.
// Vectorized: each thread computes 16 consecutive pixels (quarter row) via a
// shift-register conv; float4 loads and stores.
__global__ __launch_bounds__(256) void conv_kv_kernel(const float* __restrict__ xkv,
                               const float* __restrict__ wk, const float* __restrict__ bk,
                               const float* __restrict__ wv, const float* __restrict__ bv,
                               float* __restrict__ kb, float* __restrict__ vb) {
    int idx = blockIdx.x * 256 + threadIdx.x;   // over B*K*64*4 = 524288
    int xs = (idx & 3) << 4;        // 0,16,32,48
    int y  = (idx >> 2) & 63;
    int k  = (idx >> 8) & 127;      // uniform per wave
    int b  = idx >> 15;
    const float* wkp = wk + k * 9;
    const float* wvp = wv + k * 9;
    const float* xp  = xkv + (size_t)(b * K_ + k) * N_;
    float ak[16], av[16];
    float bk0 = bk[k], bv0 = bv[k];
#pragma unroll
    for (int i = 0; i < 16; ++i) { ak[i] = bk0; av[i] = bv0; }
#pragma unroll
    for (int dy = 0; dy < 3; ++dy) {
        int yy = y + dy - 1;
        if (yy < 0 || yy > 63) continue;
        const float* row = xp + yy * 64 + xs;
        const float4* r4 = (const float4*)row;
        float4 m0 = r4[0], m1 = r4[1], m2 = r4[2], m3 = r4[3];
        float xrow[18];
        xrow[0] = (xs == 0) ? 0.f : row[-1];
        xrow[1] = m0.x;  xrow[2] = m0.y;  xrow[3] = m0.z;  xrow[4] = m0.w;
        xrow[5] = m1.x;  xrow[6] = m1.y;  xrow[7] = m1.z;  xrow[8] = m1.w;
        xrow[9] = m2.x;  xrow[10] = m2.y; xrow[11] = m2.z; xrow[12] = m2.w;
        xrow[13] = m3.x; xrow[14] = m3.y; xrow[15] = m3.z; xrow[16] = m3.w;
        xrow[17] = (xs == 48) ? 0.f : row[16];
        float ka = wkp[dy * 3], kb_ = wkp[dy * 3 + 1], kc_ = wkp[dy * 3 + 2];
        float va = wvp[dy * 3], vb_ = wvp[dy * 3 + 1], vc_ = wvp[dy * 3 + 2];
#pragma unroll
        for (int i = 0; i < 16; ++i) {
            ak[i] += xrow[i] * ka + xrow[i + 1] * kb_ + xrow[i + 2] * kc_;
            av[i] += xrow[i] * va + xrow[i + 1] * vb_ + xrow[i + 2] * vc_;
        }
    }
    size_t o = (size_t)(b * K_ + k) * N_ + y * 64 + xs;
    float4* kd = (float4*)(kb + o);
    float4* vd = (float4*)(vb + o);
#pragma unroll
    for (int m = 0; m < 4; ++m) {
        kd[m] = make_float4(ak[4*m], ak[4*m+1], ak[4*m+2], ak[4*m+3]);
        vd[m] = make_float4(av[4*m], av[4*m+1], av[4*m+2], av[4*m+3]);
    }
}

// ---------------------------------------------------------------------------
// K2: partial logits. Block = (b, 64-channel tile, 4-image-row n-chunk),
// processed in HALF-rows of 32 n so LDS = 24 KiB -> 6 blocks/CU (75% occ cap
// vs 37.5% for the 48 KiB full-row tile). No prefetch registers (spill trap,
// r2/r3) — occupancy hides the stage latency.
// blockIdx decode puts the 8 kb-sharing c-tiles at stride 16 (same XCD L2).
__global__ __launch_bounds__(256) void qk6_kernel(const float* __restrict__ xq,
                                                  const float* __restrict__ wq,
                                                  const float* __restrict__ bq,
                                                  const float* __restrict__ kb,
                                                  float* __restrict__ part) {
    __shared__ float qs[32][64];    // [n within half-row][c]   8 KiB
    __shared__ float ks[32][128];   // [n within half-row][k]  16 KiB
    int blk = blockIdx.x;
    int ns  = blk & 15;             // 16 n-chunks (4 image rows each)
    int ct  = (blk >> 4) & 7;       // 8 c-tiles of 64; stride 16 => same XCD
    int b   = blk >> 7;
    int c0  = ct * 64;
    int r0  = ns * 4;
    int tid = threadIdx.x;

    // conv staging role: channel c_l, 8-pixel x-segment (per half-row)
    int c_l = tid >> 2;             // 0..63
    int xb8 = (tid & 3) << 3;       // 0,8,16,24 within half-row
    // k staging role: k-row, 16-pixel half of the half-row
    int k_l = tid >> 1;             // 0..127
    int nh  = (tid & 1) << 4;       // 0,16
    // compute role: 16 c-groups x 16 k-groups
    int cg4 = (tid & 15) * 4;       // c offset within tile
    int kg8 = (tid >> 4) * 8;       // k offset

    const float* wp = wq + (size_t)(c0 + c_l) * 9;
    float w00=wp[0],w01=wp[1],w02=wp[2],w10=wp[3],w11=wp[4],w12=wp[5],w20=wp[6],w21=wp[7],w22=wp[8];
    float bias = bq[c0 + c_l];
    const float* xqp = xq + ((size_t)(b * C_) + c0 + c_l) * N_;
    const float* kbp = kb + ((size_t)(b * K_) + k_l) * N_;

    float acc[4][8];
#pragma unroll
    for (int i = 0; i < 4; ++i)
#pragma unroll
        for (int j = 0; j < 8; ++j) acc[i][j] = 0.f;

    for (int rr = 0; rr < 4; ++rr) {
        int r = r0 + rr;
#pragma unroll
        for (int h = 0; h < 2; ++h) {
            __syncthreads();
            // ---- stage ks[n][k]: 32-px half of row r, k-plane k_l ----
            {
                const float4* src = (const float4*)(kbp + r * 64 + h * 32 + nh);
#pragma unroll
                for (int m = 0; m < 4; ++m) {
                    float4 v = src[m];
                    int nn = nh + m * 4;
                    ks[nn][k_l] = v.x; ks[nn + 1][k_l] = v.y;
                    ks[nn + 2][k_l] = v.z; ks[nn + 3][k_l] = v.w;
                }
            }
            // ---- stage qs[n][c]: conv on the fly, 8 px, channel c_l ----
            {
                int x0 = xb8 + h * 32;
                float a8[8];
#pragma unroll
                for (int i = 0; i < 8; ++i) a8[i] = bias;
#pragma unroll
                for (int dy = 0; dy < 3; ++dy) {
                    int yy = r + dy - 1;
                    if (yy < 0 || yy > 63) continue;
                    const float* row = xqp + yy * 64;
                    float wa = (dy == 0) ? w00 : (dy == 1) ? w10 : w20;
                    float wb = (dy == 0) ? w01 : (dy == 1) ? w11 : w21;
                    float wc = (dy == 0) ? w02 : (dy == 1) ? w12 : w22;
                    float p = (x0 == 0) ? 0.f : row[x0 - 1];
                    float c = row[x0];
#pragma unroll
                    for (int i = 0; i < 8; ++i) {
                        int x = x0 + i;
                        float nx = (x == 63) ? 0.f : row[x + 1];
                        a8[i] += p * wa + c * wb + nx * wc;
                        p = c; c = nx;
                    }
                }
#pragma unroll
                for (int i = 0; i < 8; ++i) qs[xb8 + i][c_l] = a8[i];
            }
            __syncthreads();
            // ---- accumulate 4c x 8k outer products over this half-row ----
#pragma unroll 4
            for (int nn = 0; nn < 32; ++nn) {
                float4 q4  = *(const float4*)&qs[nn][cg4];
                float4 k4a = *(const float4*)&ks[nn][kg8];
                float4 k4b = *(const float4*)&ks[nn][kg8 + 4];
                float qa[4] = {q4.x, q4.y, q4.z, q4.w};
                float kk[8] = {k4a.x, k4a.y, k4a.z, k4a.w, k4b.x, k4b.y, k4b.z, k4b.w};
#pragma unroll
                for (int i = 0; i < 4; ++i)
#pragma unroll
                    for (int j = 0; j < 8; ++j) acc[i][j] += qa[i] * kk[j];
            }
        }
    }
    // write partials: part[ns][b][c][k]
    float* dst = part + (((size_t)ns * B_ + b) * C_ + c0 + cg4) * K_ + kg8;
#pragma unroll
    for (int i = 0; i < 4; ++i) {
        *(float4*)(dst + (size_t)i * K_)     = make_float4(acc[i][0], acc[i][1], acc[i][2], acc[i][3]);
        *(float4*)(dst + (size_t)i * K_ + 4) = make_float4(acc[i][4], acc[i][5], acc[i][6], acc[i][7]);
    }
}

// ---------------------------------------------------------------------------
// K3: reduce NSPLIT partials, scale by 1/sqrt(128), softmax over k (128)
// per (b,c) row. One wave per row.
__global__ void softmax_kernel(const float* __restrict__ part, float* __restrict__ aw) {
    int tid  = threadIdx.x;
    int wave = tid >> 6;
    int lane = tid & 63;
    int row  = blockIdx.x * 4 + wave;   // over B*C = 8192
    float v0 = 0.f, v1 = 0.f;
#pragma unroll
    for (int ns = 0; ns < NSPLIT; ++ns) {
        const float* p = part + ((size_t)ns * B_ * C_ + row) * K_;
        v0 += p[lane];
        v1 += p[lane + 64];
    }
    const float scale = 0.08838834764831845f; // 1/sqrt(128)
    v0 *= scale; v1 *= scale;
    float m = fmaxf(v0, v1);
#pragma unroll
    for (int s = 32; s >= 1; s >>= 1) m = fmaxf(m, __shfl_xor(m, s, 64));
    float e0 = __expf(v0 - m), e1 = __expf(v1 - m);
    float s = e0 + e1;
#pragma unroll
    for (int t = 32; t >= 1; t >>= 1) s += __shfl_xor(s, t, 64);
    float inv = 1.0f / s;
    float* q = aw + (size_t)row * K_;
    q[lane] = e0 * inv;
    q[lane + 64] = e1 * inv;
}

// ---------------------------------------------------------------------------
// K4: per (b,k) column over c (512): find 51st-largest exactly via binary
// search on float bit pattern (positive floats order as uints), zero the rest.
__global__ void topk_mask_kernel(float* __restrict__ aw) {
    int tid  = threadIdx.x;
    int wave = tid >> 6, lane = tid & 63;
    int col  = blockIdx.x * 4 + wave;   // over B*K = 2048
    int b = col >> 7, k = col & 127;
    float* base = aw + (size_t)(b * C_) * K_ + k;
    unsigned u[8];
#pragma unroll
    for (int j = 0; j < 8; ++j)
        u[j] = __float_as_uint(base[(size_t)(j * 64 + lane) * K_]);
    unsigned T = 0;
#pragma unroll
    for (int bit = 31; bit >= 0; --bit) {
        unsigned cand = T | (1u << bit);
        int cnt = 0;
#pragma unroll
        for (int j = 0; j < 8; ++j) cnt += (u[j] >= cand) ? 1 : 0;
#pragma unroll
        for (int s = 32; s >= 1; s >>= 1) cnt += __shfl_xor(cnt, s, 64);
        if (cnt >= NKEEP) T = cand;
    }
#pragma unroll
    for (int j = 0; j < 8; ++j)
        if (u[j] < T) base[(size_t)(j * 64 + lane) * K_] = 0.0f;
}

// ---------------------------------------------------------------------------
// K5: attn_out = aw_masked @ v ; out0 = x_q + attn_out.
// LDS-free, barrier-free streaming GEMM. Per thread: 4c x 8n tile over all
// 128 k. aw rows are half-wave-broadcast loads (32 lanes share an address);
// vb rows are fully coalesced (32 lanes x 8 consecutive floats = 1 KiB).
// The 16 c-blocks sharing a (b,n0) vb slice (131 KB) sit at blockIdx stride
// 16 == 0 mod 8 -> same XCD -> L2-served. Same ascending-k summation order
// as the LDS version (bitwise-identical accumulation).
__global__ __launch_bounds__(256) void av2_kernel(const float* __restrict__ aw,
                                                  const float* __restrict__ vb,
                                                  const float* __restrict__ xq,
                                                  float* __restrict__ out) {
    int blk  = blockIdx.x;
    int b    = blk >> 8;
    int rest = blk & 255;
    int c0 = (rest >> 4) * 32;
    int n0 = (rest & 15) * 256;
    int tid = threadIdx.x;
    int cg = tid >> 5;              // 0..7, cbase = cg*4
    int ng = tid & 31;              // nbase = ng*8

    const float* awp = aw + (size_t)(b * C_ + c0 + cg * 4) * K_;
    const float* vbp = vb + (size_t)(b * K_) * N_ + n0 + ng * 8;

    float acc[4][8];
#pragma unroll
    for (int i = 0; i < 4; ++i)
#pragma unroll
        for (int j = 0; j < 8; ++j) acc[i][j] = 0.f;

    for (int kc = 0; kc < K_; kc += 4) {
        float4 a0 = *(const float4*)(awp + 0 * K_ + kc);
        float4 a1 = *(const float4*)(awp + 1 * K_ + kc);
        float4 a2 = *(const float4*)(awp + 2 * K_ + kc);
        float4 a3 = *(const float4*)(awp + 3 * K_ + kc);
#pragma unroll
        for (int j = 0; j < 4; ++j) {
            const float* vrow = vbp + (size_t)(kc + j) * N_;
            float4 v0 = *(const float4*)(vrow);
            float4 v1 = *(const float4*)(vrow + 4);
            float aa[4];
            aa[0] = (j == 0) ? a0.x : (j == 1) ? a0.y : (j == 2) ? a0.z : a0.w;
            aa[1] = (j == 0) ? a1.x : (j == 1) ? a1.y : (j == 2) ? a1.z : a1.w;
            aa[2] = (j == 0) ? a2.x : (j == 1) ? a2.y : (j == 2) ? a2.z : a2.w;
            aa[3] = (j == 0) ? a3.x : (j == 1) ? a3.y : (j == 2) ? a3.z : a3.w;
            float av[8] = {v0.x, v0.y, v0.z, v0.w, v1.x, v1.y, v1.z, v1.w};
#pragma unroll
            for (int i = 0; i < 4; ++i)
#pragma unroll
                for (int jj = 0; jj < 8; ++jj) acc[i][jj] += aa[i] * av[jj];
        }
    }
    // epilogue: out = x_q + acc, vectorized
#pragma unroll
    for (int i = 0; i < 4; ++i) {
        int c = c0 + cg * 4 + i;
        size_t base = (size_t)(b * C_ + c) * N_ + n0 + ng * 8;
        const float4* xp4 = (const float4*)(xq + base);
        float4* op4 = (float4*)(out + base);
        float4 x0 = xp4[0], x1 = xp4[1];
        float4 o0, o1;
        o0.x = x0.x + acc[i][0]; o0.y = x0.y + acc[i][1];
        o0.z = x0.z + acc[i][2]; o0.w = x0.w + acc[i][3];
        o1.x = x1.x + acc[i][4]; o1.y = x1.y + acc[i][5];
        o1.z = x1.z + acc[i][6]; o1.w = x1.w + acc[i][7];
        op4[0] = o0; op4[1] = o1;
    }
}

// ---------------------------------------------------------------------------
extern "C" void kernel_launch(void* const* d_in, const int* in_sizes, int n_in,
                              void* d_out, int out_size, void* d_ws, size_t ws_size,
                              hipStream_t stream) {
    const float* xq  = (const float*)d_in[0];
    const float* xkv = (const float*)d_in[1];
    const float* wq  = (const float*)d_in[2];
    const float* bq  = (const float*)d_in[3];
    const float* wk  = (const float*)d_in[4];
    const float* bk  = (const float*)d_in[5];
    const float* wv  = (const float*)d_in[6];
    const float* bv  = (const float*)d_in[7];

    float* out0 = (float*)d_out;                       // [16,512,64,64]
    float* aw   = out0 + (size_t)B_ * C_ * N_;         // [16,512,128]

    float* kb = (float*)d_ws;                          // [16,128,4096]
    float* vb = kb + (size_t)B_ * K_ * N_;             // [16,128,4096]
    // qk partials scratch: reuse out0's memory (67 MB of its 134 MB);
    // K5 fully overwrites out0 afterwards and never reads it.
    float* part = out0;                                // [NSPLIT][16][512][128]

    // 1. depthwise conv for k, v (16 px/thread, vectorized)
    conv_kv_kernel<<<(B_ * K_ * 64 * 4) / 256, 256, 0, stream>>>(xkv, wk, bk, wv, bv, kb, vb);
    // 2. partial logits, q conv fused; 16b x 8 c-tiles x 16 n-chunks
    qk6_kernel<<<B_ * 128, 256, 0, stream>>>(xq, wq, bq, kb, part);
    // 3. reduce partials + scale + softmax over k
    softmax_kernel<<<(B_ * C_) / 4, 256, 0, stream>>>(part, aw);
    // 4. top-51 along c per (b,k), mask in place
    topk_mask_kernel<<<(B_ * K_) / 4, 256, 0, stream>>>(aw);
    // 5. attn_out = aw @ v + x_q (LDS-free streaming)
    av2_kernel<<<B_ * 256, 256, 0, stream>>>(aw, vb, xq, out0);
}